// Round 1
// baseline (2229.723 us; speedup 1.0000x reference)
//
#include <hip/hip_runtime.h>
#include <cstdint>

#define BH  16
#define SEQ 2048
#define DIM 64
#define OUT_ELEMS (BH*SEQ*DIM)   // 2097152 floats; attn follows at this offset

// XOR swizzle on the S row index: perturb float-index bits 2-4 with c bits 6-8
// so the PV phase's stride-256B reads across column-partitions are bank-conflict-free.
__device__ __forceinline__ int SW(int c){ return c ^ (((c >> 6) & 7) << 2); }

// ---------------- Kernel A1: partial M = k^T q  (per batch, per 256-row K chunk) ----
__global__ __launch_bounds__(256) void kA1(const float* __restrict__ kk,
                                           const float* __restrict__ qq,
                                           float* __restrict__ part){
  __shared__ __align__(16) float kl[64][68];  // +4 pad: breaks store-phase bank aliasing
  __shared__ __align__(16) float ql[64][68];
  const int b   = blockIdx.y;
  const int ch  = blockIdx.x;          // 8 chunks of 256 rows
  const int tid = threadIdx.x;
  const int j     = tid & 63;          // e (q-col) index
  const int ibase = (tid >> 6) * 16;   // d (k-col) base
  const int lrow  = tid >> 2;
  const int lcol  = (tid & 3) * 16;
  const float* kb = kk + (size_t)b*SEQ*DIM;
  const float* qb = qq + (size_t)b*SEQ*DIM;
  float acc[16];
  #pragma unroll
  for (int i=0;i<16;i++) acc[i]=0.f;
  for (int sub=0; sub<4; ++sub){
    const int l0 = ch*256 + sub*64;
    const float4* ks = (const float4*)(kb + (size_t)(l0+lrow)*DIM + lcol);
    const float4* qs = (const float4*)(qb + (size_t)(l0+lrow)*DIM + lcol);
    float4 kv[4], qv[4];
    #pragma unroll
    for (int i=0;i<4;i++){ kv[i]=ks[i]; qv[i]=qs[i]; }
    __syncthreads();
    #pragma unroll
    for (int i=0;i<4;i++){
      *(float4*)&kl[lrow][lcol+4*i] = kv[i];
      *(float4*)&ql[lrow][lcol+4*i] = qv[i];
    }
    __syncthreads();
    for (int t=0; t<64; ++t){
      const float qv1 = ql[t][j];
      #pragma unroll
      for (int ii=0; ii<16; ++ii)
        acc[ii] += kl[t][ibase+ii] * qv1;   // kl reads are wave-uniform broadcast
    }
  }
  float* pp = part + (size_t)(b*8+ch)*4096;
  #pragma unroll
  for (int ii=0; ii<16; ++ii)
    pp[(ibase+ii)*64 + j] = acc[ii];
}

// ---------------- Kernel A2: reduce partials, fold 1/temper^2 ----------------------
__global__ __launch_bounds__(256) void kA2(const float* __restrict__ part,
                                           float* __restrict__ M){
  const int idx = blockIdx.x*256 + threadIdx.x;   // 16*4096 = 65536
  const int b = idx >> 12, o = idx & 4095;
  float s = 0.f;
  #pragma unroll
  for (int ch=0; ch<8; ++ch)
    s += part[(size_t)(b*8+ch)*4096 + o];
  M[(size_t)b*4096 + o] = s * (1.0f/64.0f);
}

// ---------------- Kernel B: S = (qM)p^T, softmax, attn write, out = attn v ---------
__global__ __launch_bounds__(256,2) void kB(const float* __restrict__ q,
                                            const float* __restrict__ pos,
                                            const float* __restrict__ v,
                                            const float* __restrict__ M,
                                            float* __restrict__ outp,
                                            float* __restrict__ attn){
  __shared__ __align__(16) float S[8][2048];      // 64 KB: logits -> exp values
  __shared__ __align__(16) float Tt[8][64];       // T = qM/64 for this row block
  __shared__ __align__(16) float qr[8][64];
  __shared__ __align__(16) float red2[4][8][64];  // PV cross-wave partials
  __shared__ float red[4][8];
  __shared__ float mrow[8];
  __shared__ float linv[8];

  const int b    = blockIdx.y;
  const int r0   = blockIdx.x * 8;
  const int tid  = threadIdx.x;
  const int lane = tid & 63;
  const int wid  = tid >> 6;

  // ---- stage M (into S scratch region) + q rows ----
  {
    const float4* Mg = (const float4*)(M + (size_t)b*4096);
    float4* Sl = (float4*)&S[0][0];
    #pragma unroll
    for (int i=0;i<4;i++) Sl[tid + 256*i] = Mg[tid + 256*i];
    if (tid < 128){
      const float4* qg = (const float4*)(q + ((size_t)b*SEQ + r0)*DIM);
      ((float4*)&qr[0][0])[tid] = qg[tid];
    }
  }
  __syncthreads();

  // ---- T[8][64] = qr * M ----
  {
    const float* Ml = &S[0][0];
    #pragma unroll
    for (int oo=0;oo<2;oo++){
      const int o = tid + 256*oo;
      const int r = o >> 6, e = o & 63;
      float a = 0.f;
      #pragma unroll
      for (int d=0; d<64; ++d)
        a += qr[r][d] * Ml[d*64 + e];
      Tt[r][e] = a;
    }
  }
  __syncthreads();

  // ---- logits S[r][c] = T[r] . pos[c], track per-thread row max ----
  float mloc[8];
  #pragma unroll
  for (int r=0;r<8;r++) mloc[r] = -3.0e38f;
  const float* pb = pos + (size_t)b*SEQ*DIM;
  for (int jj=0; jj<4; ++jj){
    const int c0 = tid + 256*(2*jj);
    const int c1 = tid + 256*(2*jj+1);
    float4 pv0[16], pv1[16];
    const float4* pg0 = (const float4*)(pb + (size_t)c0*DIM);
    const float4* pg1 = (const float4*)(pb + (size_t)c1*DIM);
    #pragma unroll
    for (int i=0;i<16;i++){ pv0[i]=pg0[i]; pv1[i]=pg1[i]; }
    #pragma unroll
    for (int r=0;r<8;r++){
      float a0=0.f, a1=0.f;
      #pragma unroll
      for (int d4=0; d4<16; ++d4){
        const float4 tf = *(const float4*)&Tt[r][4*d4];  // wave-uniform broadcast
        a0 += tf.x*pv0[d4].x + tf.y*pv0[d4].y + tf.z*pv0[d4].z + tf.w*pv0[d4].w;
        a1 += tf.x*pv1[d4].x + tf.y*pv1[d4].y + tf.z*pv1[d4].z + tf.w*pv1[d4].w;
      }
      S[r][SW(c0)] = a0;
      S[r][SW(c1)] = a1;
      mloc[r] = fmaxf(mloc[r], fmaxf(a0, a1));
    }
  }

  // ---- row max reduction ----
  #pragma unroll
  for (int r=0;r<8;r++){
    float m = mloc[r];
    #pragma unroll
    for (int off=32; off>0; off>>=1)
      m = fmaxf(m, __shfl_xor(m, off, 64));
    if (lane==0) red[wid][r] = m;
  }
  __syncthreads();
  if (tid < 8)
    mrow[tid] = fmaxf(fmaxf(red[0][tid],red[1][tid]), fmaxf(red[2][tid],red[3][tid]));
  __syncthreads();

  // ---- exp in place + row sums (each thread touches only its own cells) ----
  float mreg[8], sloc[8];
  #pragma unroll
  for (int r=0;r<8;r++){ mreg[r]=mrow[r]; sloc[r]=0.f; }
  for (int j=0;j<8;++j){
    const int cs = SW(tid + 256*j);
    #pragma unroll
    for (int r=0;r<8;r++){
      const float e = __expf(S[r][cs] - mreg[r]);
      S[r][cs] = e;
      sloc[r] += e;
    }
  }
  #pragma unroll
  for (int r=0;r<8;r++){
    float s = sloc[r];
    #pragma unroll
    for (int off=32; off>0; off>>=1)
      s += __shfl_xor(s, off, 64);
    if (lane==0) red[wid][r] = s;
  }
  __syncthreads();
  if (tid < 8)
    linv[tid] = 1.0f / (red[0][tid]+red[1][tid]+red[2][tid]+red[3][tid]);
  __syncthreads();

  // ---- write attn = e * (1/l), coalesced ----
  float lreg[8];
  #pragma unroll
  for (int r=0;r<8;r++) lreg[r] = linv[r];
  float* ab = attn + ((size_t)b*SEQ + r0)*(size_t)SEQ;
  for (int j=0;j<8;++j){
    const int c  = tid + 256*j;
    const int cs = SW(c);
    #pragma unroll
    for (int r=0;r<8;r++)
      ab[(size_t)r*SEQ + c] = S[r][cs] * lreg[r];
  }

  // ---- PV: out[r][d] = (1/l) sum_c e[r][c] v[c][d] ----
  // thread = (dgrp: 8 d's) x (cpart: 64 c's); register tile 8r x 8d
  const int dgrp  = tid & 7;
  const int cpart = tid >> 3;          // 0..31
  float acc2[8][8];
  #pragma unroll
  for (int r=0;r<8;r++)
    #pragma unroll
    for (int i=0;i<8;i++) acc2[r][i]=0.f;
  const float* vb = v + (size_t)b*SEQ*DIM;
  for (int ch=0; ch<16; ++ch){
    const int cbase = cpart*64 + ch*4;
    float4 va[4][2];
    #pragma unroll
    for (int i=0;i<4;i++){
      const float* vr = vb + (size_t)(cbase+i)*DIM + dgrp*8;
      va[i][0] = *(const float4*)vr;
      va[i][1] = *(const float4*)(vr+4);
    }
    #pragma unroll
    for (int r=0;r<8;r++){
      const float4 s4 = *(const float4*)&S[r][SW(cbase)];  // swizzle -> conflict-free
      const float sc[4] = {s4.x, s4.y, s4.z, s4.w};
      #pragma unroll
      for (int i=0;i<4;i++){
        acc2[r][0] += sc[i]*va[i][0].x;
        acc2[r][1] += sc[i]*va[i][0].y;
        acc2[r][2] += sc[i]*va[i][0].z;
        acc2[r][3] += sc[i]*va[i][0].w;
        acc2[r][4] += sc[i]*va[i][1].x;
        acc2[r][5] += sc[i]*va[i][1].y;
        acc2[r][6] += sc[i]*va[i][1].z;
        acc2[r][7] += sc[i]*va[i][1].w;
      }
    }
  }
  // butterfly over cparts within the wave (lane bits 3..5), dgrp preserved
  #pragma unroll
  for (int r=0;r<8;r++)
    #pragma unroll
    for (int i=0;i<8;i++){
      float x = acc2[r][i];
      x += __shfl_xor(x, 8, 64);
      x += __shfl_xor(x, 16, 64);
      x += __shfl_xor(x, 32, 64);
      acc2[r][i] = x;
    }
  if (lane < 8){                        // lane == dgrp for these lanes
    #pragma unroll
    for (int r=0;r<8;r++)
      #pragma unroll
      for (int i=0;i<8;i++)
        red2[wid][r][lane*8+i] = acc2[r][i];
  }
  __syncthreads();
  {
    const int o = tid*2;                // 512 outputs, 2 per thread
    const int r = o >> 6;
    const int d = o & 63;
    const float li = linv[r];
    float2 res;
    res.x = (red2[0][r][d  ]+red2[1][r][d  ]+red2[2][r][d  ]+red2[3][r][d  ]) * li;
    res.y = (red2[0][r][d+1]+red2[1][r][d+1]+red2[2][r][d+1]+red2[3][r][d+1]) * li;
    float* ob = outp + ((size_t)b*SEQ + r0)*DIM;
    *(float2*)(ob + (size_t)r*DIM + d) = res;
  }
}

extern "C" void kernel_launch(void* const* d_in, const int* in_sizes, int n_in,
                              void* d_out, int out_size, void* d_ws, size_t ws_size,
                              hipStream_t stream){
  const float* q = (const float*)d_in[0];
  const float* k = (const float*)d_in[1];
  const float* v = (const float*)d_in[2];
  const float* p = (const float*)d_in[3];
  float* out  = (float*)d_out;
  float* attn = out + OUT_ELEMS;          // second tuple element
  float* M    = (float*)d_ws;             // 16*64*64 fp32 = 256 KB
  float* part = attn;                     // M-partials scratch; kB overwrites later

  kA1<<<dim3(8,16),  256, 0, stream>>>(k, q, part);
  kA2<<<dim3(256),   256, 0, stream>>>(part, M);
  kB <<<dim3(256,16),256, 0, stream>>>(q, p, v, M, out, attn);
}